// Round 3
// baseline (1494.987 us; speedup 1.0000x reference)
//
#include <hip/hip_runtime.h>

#define NN 100000
#define NE 1600000
#define D 48
#define BK_SHIFT 6
#define BK_NODES 64
#define NBK 1563      // ceil(NN / 64)
#define CAP 1344      // per-bucket arena capacity; mean 1024, sd ~32 -> +10 sd
#define EPB 4096      // edges per block in binning pass -> 391 blocks
#define ST 72         // LDS activation row stride in f16

typedef _Float16 f16x8 __attribute__((ext_vector_type(8)));
typedef float f32x4 __attribute__((ext_vector_type(4)));

// ---------------- prep: pack weights (blocks 0..7), zero bucketLen (block 8),
// ---------------- x -> f16 (blocks 9..) ----------------

__global__ __launch_bounds__(256) void prep(
    const float* __restrict__ x,
    const float* __restrict__ w11, const float* __restrict__ w12,
    const float* __restrict__ w21, const float* __restrict__ w22,
    const float* __restrict__ w31, const float* __restrict__ w32,
    const float* __restrict__ wf1, const float* __restrict__ wf2,
    _Float16* __restrict__ wp, uint4* __restrict__ outh,
    int* __restrict__ bucketLen) {
    int b = blockIdx.x;
    int tid = threadIdx.x;
    if (b < 8) {
        const float* W;
        int NL = 48;
        switch (b) {
            case 0: W = w11; break;
            case 1: W = w12; break;
            case 2: W = w21; break;
            case 3: W = w22; break;
            case 4: W = w31; break;
            case 5: W = w32; break;
            case 6: W = wf1; break;
            default: W = wf2; NL = 16; break;
        }
        _Float16* T = wp + b * 3072;
        int total = 64 * NL;  // (8 k-groups * 8 j) * NL
        for (int i = tid; i < total; i += 256) {
            int j = i & 7;
            int m = i >> 3;
            int g = m / NL;
            int nn = m - g * NL;
            int k = g * 8 + j;
            T[i] = (k < 48) ? (_Float16)W[k * NL + nn] : (_Float16)0.f;
        }
    } else if (b == 8) {
        for (int i = tid; i < NBK; i += 256) bucketLen[i] = 0;
    } else {
        int i = (b - 9) * 256 + tid;
        if (i < NN * 6) {
            const float4* p = (const float4*)(x + (size_t)i * 8);
            float4 a = p[0], bb = p[1];
            union { _Float16 h[8]; uint4 u; } pk;
            pk.h[0] = (_Float16)a.x; pk.h[1] = (_Float16)a.y;
            pk.h[2] = (_Float16)a.z; pk.h[3] = (_Float16)a.w;
            pk.h[4] = (_Float16)bb.x; pk.h[5] = (_Float16)bb.y;
            pk.h[6] = (_Float16)bb.z; pk.h[7] = (_Float16)bb.w;
            outh[i] = pk.u;
        }
    }
}

// ---------------- Pass B: bin edges by dst>>6 into per-bucket arenas.
// With 64-node buckets the arena IS the per-conv-block edge list: no CSR,
// no scan, no csr_from_bins. Packed word: (dstlocal 6b << 17) | src (17b).

__global__ __launch_bounds__(256) void bin_scatter(
    const int* __restrict__ src, const int* __restrict__ dst,
    int* __restrict__ bucketLen, int* __restrict__ arena) {
    __shared__ int sCnt[NBK];
    __shared__ int sBase[NBK];
    int tid = threadIdx.x;
    for (int i = tid; i < NBK; i += 256) sCnt[i] = 0;
    __syncthreads();
    int e0 = blockIdx.x * EPB;
    int eend = e0 + EPB;
    if (eend > NE) eend = NE;
    for (int i = e0 + tid; i < eend; i += 256) atomicAdd(&sCnt[dst[i] >> BK_SHIFT], 1);
    __syncthreads();
    for (int i = tid; i < NBK; i += 256) sBase[i] = atomicAdd(&bucketLen[i], sCnt[i]);
    __syncthreads();
    for (int i = tid; i < NBK; i += 256) sCnt[i] = 0;
    __syncthreads();
    for (int i = e0 + tid; i < eend; i += 256) {
        int d = dst[i];
        int b = d >> BK_SHIFT;
        int off = atomicAdd(&sCnt[b], 1) + sBase[b];
        if (off < CAP) arena[b * CAP + off] = ((d & (BK_NODES - 1)) << 17) | src[i];
    }
}

// ---------------- MFMA layer (unchanged, m89-verified mappings) ----------------
// A-frag: m = lane&15, k = (lane>>4)*8 + j; B-frag n = lane&15, same k;
// C/D: col n = lane&15, row m = (lane>>4)*4 + r.

__device__ __forceinline__ void mfma_layer48(
    const _Float16* __restrict__ wp, const float* __restrict__ bias,
    const _Float16* src, _Float16* dst, int lane) {
    int am = lane & 15, q = lane >> 4;
    f16x8 a0 = *(const f16x8*)(src + am * ST + q * 8);
    f16x8 a1 = *(const f16x8*)(src + am * ST + 32 + q * 8);
#pragma unroll
    for (int t = 0; t < 3; ++t) {
        f16x8 b0 = *(const f16x8*)(wp + ((q) * 48 + t * 16 + am) * 8);
        f16x8 b1 = *(const f16x8*)(wp + ((4 + q) * 48 + t * 16 + am) * 8);
        float bv = bias[t * 16 + am];
        f32x4 c = {bv, bv, bv, bv};
        c = __builtin_amdgcn_mfma_f32_16x16x32_f16(a0, b0, c, 0, 0, 0);
        c = __builtin_amdgcn_mfma_f32_16x16x32_f16(a1, b1, c, 0, 0, 0);
#pragma unroll
        for (int r = 0; r < 4; ++r) {
            float v = fmaxf(c[r], 0.f);
            dst[(q * 4 + r) * ST + t * 16 + am] = (_Float16)v;
        }
    }
}

// ---------------- edge-parallel aggregation into the block's 64-row slab ------
// HAf (f32, [64][48]) accumulates self + neighbors via ds_add_f32 (native LDS
// f32 atomic). Then one conversion pass produces the f16 MFMA A-slab HA with
// zeroed K-pads. HB (layer ping-pong buffer) ALIASES HAf — dead after the
// conversion; an extra barrier covers the reuse. 21.5 KB LDS -> 7 blocks/CU.

__device__ __forceinline__ void aggregate_bucket(
    const uint4* __restrict__ hin4, const int* __restrict__ arena,
    const int* __restrict__ bucketLen,
    float* HAf, _Float16* HA, _Float16* HB, int b, int base, int tid, int n) {
    // init: row = self feature (eps=0 GIN term), f32
    for (int i = tid; i < 64 * 6; i += 256) {
        int r = i / 6, c = i - (i / 6) * 6;
        int node = base + r;
        uint4 v = make_uint4(0u, 0u, 0u, 0u);
        if (node < n) v = hin4[(size_t)node * 6 + c];
        const _Float16* hp = (const _Float16*)&v;
        float* fp = HAf + r * 48 + c * 8;
#pragma unroll
        for (int u = 0; u < 8; ++u) fp[u] = (float)hp[u];
    }
    __syncthreads();
    // edge-parallel scatter: item = edge*6 + chunk; 6 consecutive lanes read one
    // edge's 96B feature row as uint4 (16B/lane, coalesced, zero lane waste).
    int len = bucketLen[b];
    if (len > CAP) len = CAP;
    const int* ar = arena + (size_t)b * CAP;
    int items = len * 6;
    for (int it = tid; it < items; it += 256) {
        int e = it / 6;
        int c = it - e * 6;
        int p = ar[e];  // 6 lanes share the word -> same L1 line, broadcast
        uint4 v = hin4[(size_t)(p & 0x1FFFF) * 6 + c];
        const _Float16* hp = (const _Float16*)&v;
        float* fp = HAf + (p >> 17) * 48 + c * 8;
#pragma unroll
        for (int u = 0; u < 8; ++u) atomicAdd(fp + u, (float)hp[u]);
    }
    __syncthreads();
    // convert f32 -> f16 A-slab + zero K-pads of HA
    for (int i = tid; i < 64 * 6; i += 256) {
        int r = i / 6, c = i - (i / 6) * 6;
        const float* fp = HAf + r * 48 + c * 8;
        union { _Float16 h[8]; uint4 u; } pk;
#pragma unroll
        for (int u = 0; u < 8; ++u) pk.h[u] = (_Float16)fp[u];
        *(uint4*)(HA + r * ST + c * 8) = pk.u;
    }
    for (int i = tid; i < 64 * 12; i += 256) {
        int r = i / 12, c = i - (i / 12) * 12;
        *(unsigned*)(HA + r * ST + 48 + c * 2) = 0u;
    }
    __syncthreads();
    // HB aliases HAf: all HAf reads are done, now safe to zero HB's K-pads
    for (int i = tid; i < 64 * 12; i += 256) {
        int r = i / 12, c = i - (i / 12) * 12;
        *(unsigned*)(HB + r * ST + 48 + c * 2) = 0u;
    }
    __syncthreads();
}

// conv: aggregate -> relu(@W1+b1) -> relu(@W2+b2) -> f16 features (ping-pong)
__global__ __launch_bounds__(256) void conv_fused(
    const uint4* __restrict__ hin4, const int* __restrict__ arena,
    const int* __restrict__ bucketLen,
    const _Float16* __restrict__ wp1, const float* __restrict__ B1,
    const _Float16* __restrict__ wp2, const float* __restrict__ B2,
    _Float16* __restrict__ hout, int n) {
    __shared__ __align__(16) _Float16 HA[64 * ST];
    __shared__ __align__(16) float U[64 * 48];  // HAf during agg, then HB
    _Float16* HB = (_Float16*)U;
    int tid = threadIdx.x;
    int b = blockIdx.x;
    int base = b << BK_SHIFT;
    aggregate_bucket(hin4, arena, bucketLen, U, HA, HB, b, base, tid, n);

    int lane = tid & 63, wv = tid >> 6;
    _Float16* s0 = HA + wv * 16 * ST;
    _Float16* s1 = HB + wv * 16 * ST;
    mfma_layer48(wp1, B1, s0, s1, lane);
    __builtin_amdgcn_wave_barrier();

    // layer 2 -> hout (f16), relu
    int am = lane & 15, q = lane >> 4;
    f16x8 a0 = *(const f16x8*)(s1 + am * ST + q * 8);
    f16x8 a1 = *(const f16x8*)(s1 + am * ST + 32 + q * 8);
    int g0 = base + wv * 16;
#pragma unroll
    for (int t = 0; t < 3; ++t) {
        f16x8 b0 = *(const f16x8*)(wp2 + ((q) * 48 + t * 16 + am) * 8);
        f16x8 b1 = *(const f16x8*)(wp2 + ((4 + q) * 48 + t * 16 + am) * 8);
        float bv = B2[t * 16 + am];
        f32x4 c = {bv, bv, bv, bv};
        c = __builtin_amdgcn_mfma_f32_16x16x32_f16(a0, b0, c, 0, 0, 0);
        c = __builtin_amdgcn_mfma_f32_16x16x32_f16(a1, b1, c, 0, 0, 0);
#pragma unroll
        for (int r = 0; r < 4; ++r) {
            int node = g0 + q * 4 + r;
            if (node < n) {
                float v = fmaxf(c[r], 0.f);
                hout[(size_t)node * D + t * 16 + am] = (_Float16)v;
            }
        }
    }
}

// tail: aggregate + conv3 MLP (48->48->48 relu) + head (48->48 relu -> 16), f32 out
__global__ __launch_bounds__(256) void tail_fused(
    const uint4* __restrict__ hin4, const int* __restrict__ arena,
    const int* __restrict__ bucketLen,
    const _Float16* __restrict__ wp1, const float* __restrict__ B1,
    const _Float16* __restrict__ wp2, const float* __restrict__ B2,
    const _Float16* __restrict__ wp3, const float* __restrict__ B3,
    const _Float16* __restrict__ wp4, const float* __restrict__ B4,
    float* __restrict__ out, int n) {
    __shared__ __align__(16) _Float16 HA[64 * ST];
    __shared__ __align__(16) float U[64 * 48];  // HAf during agg, then HB
    _Float16* HB = (_Float16*)U;
    int tid = threadIdx.x;
    int b = blockIdx.x;
    int base = b << BK_SHIFT;
    aggregate_bucket(hin4, arena, bucketLen, U, HA, HB, b, base, tid, n);

    int lane = tid & 63, wv = tid >> 6;
    _Float16* s0 = HA + wv * 16 * ST;
    _Float16* s1 = HB + wv * 16 * ST;
    mfma_layer48(wp1, B1, s0, s1, lane);
    __builtin_amdgcn_wave_barrier();
    mfma_layer48(wp2, B2, s1, s0, lane);
    __builtin_amdgcn_wave_barrier();
    mfma_layer48(wp3, B3, s0, s1, lane);
    __builtin_amdgcn_wave_barrier();

    // final 48 -> 16, no relu, f32 out
    int am = lane & 15, q = lane >> 4;
    f16x8 a0 = *(const f16x8*)(s1 + am * ST + q * 8);
    f16x8 a1 = *(const f16x8*)(s1 + am * ST + 32 + q * 8);
    f16x8 b0 = *(const f16x8*)(wp4 + ((q) * 16 + am) * 8);
    f16x8 b1 = *(const f16x8*)(wp4 + ((4 + q) * 16 + am) * 8);
    float bv = B4[am];
    f32x4 c = {bv, bv, bv, bv};
    c = __builtin_amdgcn_mfma_f32_16x16x32_f16(a0, b0, c, 0, 0, 0);
    c = __builtin_amdgcn_mfma_f32_16x16x32_f16(a1, b1, c, 0, 0, 0);
    int g0 = base + wv * 16;
#pragma unroll
    for (int r = 0; r < 4; ++r) {
        int node = g0 + q * 4 + r;
        if (node < n) out[(size_t)node * 16 + am] = c[r];
    }
}

// ---------------- launch ----------------

extern "C" void kernel_launch(void* const* d_in, const int* in_sizes, int n_in,
                              void* d_out, int out_size, void* d_ws, size_t ws_size,
                              hipStream_t stream) {
    const int n = NN, e = NE;
    const float* x = (const float*)d_in[0];
    const int* ei = (const int*)d_in[1];
    const int* src = ei;
    const int* dst = ei + e;
    const float* w11 = (const float*)d_in[2];
    const float* b11 = (const float*)d_in[3];
    const float* w12 = (const float*)d_in[4];
    const float* b12 = (const float*)d_in[5];
    const float* w21 = (const float*)d_in[6];
    const float* b21 = (const float*)d_in[7];
    const float* w22 = (const float*)d_in[8];
    const float* b22 = (const float*)d_in[9];
    const float* w31 = (const float*)d_in[10];
    const float* b31 = (const float*)d_in[11];
    const float* w32 = (const float*)d_in[12];
    const float* b32 = (const float*)d_in[13];
    const float* wf1 = (const float*)d_in[14];
    const float* bf1 = (const float*)d_in[15];
    const float* wf2 = (const float*)d_in[16];
    const float* bf2 = (const float*)d_in[17];
    float* out = (float*)d_out;

    // workspace: ping-pong f16 feature buffers + packed weights + 64-node-bucket
    // edge arenas (CSR/rowptr/colidx eliminated)
    uint4* HAa = (uint4*)d_ws;                        // N*6 uint4
    uint4* HAb = HAa + (size_t)n * 6;                 // N*6 uint4
    _Float16* WP = (_Float16*)(HAb + (size_t)n * 6);  // 8*3072 packed weights
    int* bucketLen = (int*)(WP + 8 * 3072);           // NBK
    int* arena = bucketLen + NBK;                     // NBK*CAP
    size_t needed = (size_t)((char*)(arena + (size_t)NBK * CAP) - (char*)d_ws);
    if (needed > ws_size) return;

    const _Float16* wp11 = WP + 0 * 3072;
    const _Float16* wp12 = WP + 1 * 3072;
    const _Float16* wp21 = WP + 2 * 3072;
    const _Float16* wp22 = WP + 3 * 3072;
    const _Float16* wp31 = WP + 4 * 3072;
    const _Float16* wp32 = WP + 5 * 3072;
    const _Float16* wpf1 = WP + 6 * 3072;
    const _Float16* wpf2 = WP + 7 * 3072;

    // ---- prep + 64-node binning (2 dispatches; scan + csr kernels deleted) ----
    int gPrep = 9 + (n * 6 + 255) / 256;
    prep<<<gPrep, 256, 0, stream>>>(x, w11, w12, w21, w22, w31, w32, wf1, wf2,
                                    WP, HAa, bucketLen);
    bin_scatter<<<(e + EPB - 1) / EPB, 256, 0, stream>>>(src, dst, bucketLen, arena);

    int gConv = NBK;  // one 64-node bucket per block, 4 waves

    // ---- 3 fused convs (ping-pong HAa <-> HAb) ----
    conv_fused<<<gConv, 256, 0, stream>>>(HAa, arena, bucketLen,
                                          wp11, b11, wp12, b12, (_Float16*)HAb, n);
    conv_fused<<<gConv, 256, 0, stream>>>(HAb, arena, bucketLen,
                                          wp21, b21, wp22, b22, (_Float16*)HAa, n);
    tail_fused<<<gConv, 256, 0, stream>>>(HAa, arena, bucketLen,
                                          wp31, b31, wp32, b32,
                                          wpf1, bf1, wpf2, bf2, out, n);
}

// Round 4
// 281.018 us; speedup vs baseline: 5.3199x; 5.3199x over previous
//
#include <hip/hip_runtime.h>

#define NN 100000
#define NE 1600000
#define D 48
#define BK_SHIFT 8
#define BK_NODES 256
#define NBK 391       // ceil(NN / 256)
#define CAP 5120      // per-bucket arena capacity; expected 4096, sd ~64
#define EPB 4096      // edges per block in binning pass -> 391 blocks
#define ST 72         // LDS activation row stride in f16

typedef _Float16 f16x8 __attribute__((ext_vector_type(8)));
typedef float f32x4 __attribute__((ext_vector_type(4)));

// ---------------- prep: pack weights (blocks 0..7), zero bucketLen (block 8),
// ---------------- x -> f16 (blocks 9..) ----------------

__global__ __launch_bounds__(256) void prep(
    const float* __restrict__ x,
    const float* __restrict__ w11, const float* __restrict__ w12,
    const float* __restrict__ w21, const float* __restrict__ w22,
    const float* __restrict__ w31, const float* __restrict__ w32,
    const float* __restrict__ wf1, const float* __restrict__ wf2,
    _Float16* __restrict__ wp, uint4* __restrict__ outh,
    int* __restrict__ bucketLen) {
    int b = blockIdx.x;
    int tid = threadIdx.x;
    if (b < 8) {
        const float* W;
        int NL = 48;
        switch (b) {
            case 0: W = w11; break;
            case 1: W = w12; break;
            case 2: W = w21; break;
            case 3: W = w22; break;
            case 4: W = w31; break;
            case 5: W = w32; break;
            case 6: W = wf1; break;
            default: W = wf2; NL = 16; break;
        }
        _Float16* T = wp + b * 3072;
        int total = 64 * NL;  // (8 k-groups * 8 j) * NL
        for (int i = tid; i < total; i += 256) {
            int j = i & 7;
            int m = i >> 3;
            int g = m / NL;
            int nn = m - g * NL;
            int k = g * 8 + j;
            T[i] = (k < 48) ? (_Float16)W[k * NL + nn] : (_Float16)0.f;
        }
    } else if (b == 8) {
        for (int i = tid; i < NBK; i += 256) bucketLen[i] = 0;
    } else {
        int i = (b - 9) * 256 + tid;
        if (i < NN * 6) {
            const float4* p = (const float4*)(x + (size_t)i * 8);
            float4 a = p[0], bb = p[1];
            union { _Float16 h[8]; uint4 u; } pk;
            pk.h[0] = (_Float16)a.x; pk.h[1] = (_Float16)a.y;
            pk.h[2] = (_Float16)a.z; pk.h[3] = (_Float16)a.w;
            pk.h[4] = (_Float16)bb.x; pk.h[5] = (_Float16)bb.y;
            pk.h[6] = (_Float16)bb.z; pk.h[7] = (_Float16)bb.w;
            outh[i] = pk.u;
        }
    }
}

// ---------------- Pass B: bin edges by dst>>8 into per-bucket arenas ----------------

__global__ __launch_bounds__(256) void bin_scatter(
    const int* __restrict__ src, const int* __restrict__ dst,
    int* __restrict__ bucketLen, int* __restrict__ arena) {
    __shared__ int sCnt[NBK];
    __shared__ int sBase[NBK];
    int tid = threadIdx.x;
    for (int i = tid; i < NBK; i += 256) sCnt[i] = 0;
    __syncthreads();
    int e0 = blockIdx.x * EPB;
    int eend = e0 + EPB;
    if (eend > NE) eend = NE;
    for (int i = e0 + tid; i < eend; i += 256) atomicAdd(&sCnt[dst[i] >> BK_SHIFT], 1);
    __syncthreads();
    for (int i = tid; i < NBK; i += 256) sBase[i] = atomicAdd(&bucketLen[i], sCnt[i]);
    __syncthreads();
    for (int i = tid; i < NBK; i += 256) sCnt[i] = 0;
    __syncthreads();
    for (int i = e0 + tid; i < eend; i += 256) {
        int d = dst[i];
        int b = d >> BK_SHIFT;
        int off = atomicAdd(&sCnt[b], 1) + sBase[b];
        if (off < CAP) arena[b * CAP + off] = ((d & (BK_NODES - 1)) << 17) | src[i];
    }
}

// ---------------- parallel bucket scan ----------------

__global__ __launch_bounds__(512) void scan_buckets_par(
    const int* __restrict__ bucketLen, int* __restrict__ bucketBase,
    int* __restrict__ rowptr) {
    __shared__ int s[512];
    int t = threadIdx.x;
    int mine = (t < NBK) ? bucketLen[t] : 0;
    s[t] = mine;
    __syncthreads();
    for (int off = 1; off < 512; off <<= 1) {
        int v = (t >= off) ? s[t - off] : 0;
        __syncthreads();
        s[t] += v;
        __syncthreads();
    }
    if (t < NBK) bucketBase[t] = s[t] - mine;  // exclusive
    if (t == NBK - 1) {
        bucketBase[NBK] = s[t];
        rowptr[NN] = s[t];  // == NE
    }
}

// ---------------- Pass C: per-bucket CSR ----------------

__global__ __launch_bounds__(256) void csr_from_bins(
    const int* __restrict__ arena, const int* __restrict__ bucketLen,
    const int* __restrict__ bucketBase, int* __restrict__ rowptr,
    int* __restrict__ colidx) {
    __shared__ int sCnt[BK_NODES];
    __shared__ int sTot[256];
    int b = blockIdx.x;
    int tid = threadIdx.x;
    int len = bucketLen[b];
    if (len > CAP) len = CAP;
    const int* ar = arena + b * CAP;
    int colBase = bucketBase[b];
    int nodeBase = b << BK_SHIFT;

    sCnt[tid] = 0;
    __syncthreads();
    for (int i = tid; i < len; i += 256) atomicAdd(&sCnt[ar[i] >> 17], 1);
    __syncthreads();

    int mine = sCnt[tid];
    sTot[tid] = mine;
    __syncthreads();
    for (int off = 1; off < 256; off <<= 1) {
        int add = 0;
        if (tid >= off) add = sTot[tid - off];
        __syncthreads();
        if (tid >= off) sTot[tid] += add;
        __syncthreads();
    }
    int excl = sTot[tid] - mine;
    int node = nodeBase + tid;
    if (node < NN) rowptr[node] = colBase + excl;
    __syncthreads();
    sCnt[tid] = colBase + excl;
    __syncthreads();
    for (int i = tid; i < len; i += 256) {
        int p = ar[i];
        int pos = atomicAdd(&sCnt[p >> 17], 1);
        colidx[pos] = p & 0x1FFFF;
    }
}

// ---------------- MFMA layer (unchanged, m89-verified mappings) ----------------
// A-frag: m = lane&15, k = (lane>>4)*8 + j; B-frag n = lane&15, same k;
// C/D: col n = lane&15, row m = (lane>>4)*4 + r.

__device__ __forceinline__ void mfma_layer48(
    const _Float16* __restrict__ wp, const float* __restrict__ bias,
    const _Float16* src, _Float16* dst, int lane) {
    int am = lane & 15, q = lane >> 4;
    f16x8 a0 = *(const f16x8*)(src + am * ST + q * 8);
    f16x8 a1 = *(const f16x8*)(src + am * ST + 32 + q * 8);
#pragma unroll
    for (int t = 0; t < 3; ++t) {
        f16x8 b0 = *(const f16x8*)(wp + ((q) * 48 + t * 16 + am) * 8);
        f16x8 b1 = *(const f16x8*)(wp + ((4 + q) * 48 + t * 16 + am) * 8);
        float bv = bias[t * 16 + am];
        f32x4 c = {bv, bv, bv, bv};
        c = __builtin_amdgcn_mfma_f32_16x16x32_f16(a0, b0, c, 0, 0, 0);
        c = __builtin_amdgcn_mfma_f32_16x16x32_f16(a1, b1, c, 0, 0, 0);
#pragma unroll
        for (int r = 0; r < 4; ++r) {
            float v = fmaxf(c[r], 0.f);
            dst[(q * 4 + r) * ST + t * 16 + am] = (_Float16)v;
        }
    }
}

// ---------------- fused gather + stage v2: wave-local, no __syncthreads -------
// New geometry: lane = c*8 + s; s = edge slot (8 edges in flight per batch),
// c = 16B chunk of the 96B feature row (c<6 active; lanes 48..63 idle).
// Each active lane loads one uint4 (16B) per edge -> 6 vmem lane-ops/edge
// (vs 32 in the 4B-per-lane version). Two batches (16 edges) in flight per
// iteration; 3-step shfl_xor tree over s reduces the 8 slots; s==0 lanes add
// the self row (eps=0 GIN term) and store 16B to the wave's LDS slab.

__device__ __forceinline__ void gather_stage(const uint4* __restrict__ hin4,
                                             const int* __restrict__ rowptr,
                                             const int* __restrict__ col,
                                             _Float16* s0, _Float16* s1,
                                             int base, int wv, int lane, int n) {
    // zero K-pad halves (cols 48..71) of both slabs, 16B stores
    for (int i = lane; i < 16 * 3; i += 64) {
        int r = i / 3, cq = i % 3;
        *(uint4*)(s0 + r * ST + 48 + cq * 8) = make_uint4(0u, 0u, 0u, 0u);
        *(uint4*)(s1 + r * ST + 48 + cq * 8) = make_uint4(0u, 0u, 0u, 0u);
    }
    int s = lane & 7;   // edge slot
    int c = lane >> 3;  // row chunk (0..5 active, 6..7 idle)
    bool act = (c < 6);
    int cc = act ? c : 0;
    for (int nl = 0; nl < 16; ++nl) {
        int node = base + wv * 16 + nl;
        f16x8 acc = {0, 0, 0, 0, 0, 0, 0, 0};
        if (act && node < n) {
            int e0 = rowptr[node];
            int e1 = rowptr[node + 1];
            for (int eb = e0; eb < e1; eb += 16) {  // 16 edges (2 batches) in flight
                int ee0 = eb + s, ee1 = eb + 8 + s;
                bool ok0 = ee0 < e1, ok1 = ee1 < e1;
                int i0 = col[ok0 ? ee0 : e0];
                int i1 = col[ok1 ? ee1 : e0];
                uint4 v0 = hin4[(size_t)i0 * 6 + cc];
                uint4 v1 = hin4[(size_t)i1 * 6 + cc];
                if (!ok0) v0 = make_uint4(0u, 0u, 0u, 0u);
                if (!ok1) v1 = make_uint4(0u, 0u, 0u, 0u);
                acc += *(const f16x8*)&v0;
                acc += *(const f16x8*)&v1;
            }
        }
        // reduce over the 8 edge slots (xor tree on s; c preserved since m<8)
        union { f16x8 f; int i[4]; } a, bx;
        a.f = acc;
#pragma unroll
        for (int m = 1; m <= 4; m <<= 1) {
            bx.i[0] = __shfl_xor(a.i[0], m);
            bx.i[1] = __shfl_xor(a.i[1], m);
            bx.i[2] = __shfl_xor(a.i[2], m);
            bx.i[3] = __shfl_xor(a.i[3], m);
            a.f += bx.f;
        }
        if (s == 0 && act && node < n) {
            uint4 self = hin4[(size_t)node * 6 + c];
            a.f += *(const f16x8*)&self;
            *(uint4*)(s0 + nl * ST + c * 8) = *(const uint4*)&a.f;
        }
    }
    __builtin_amdgcn_wave_barrier();  // scheduling fence (wave-lockstep LDS idiom)
}

// conv: gather+self -> relu(@W1+b1) -> relu(@W2+b2) -> f16 features (ping-pong)
__global__ __launch_bounds__(256) void conv_fused(
    const uint4* __restrict__ hin4, const int* __restrict__ rowptr,
    const int* __restrict__ col,
    const _Float16* __restrict__ wp1, const float* __restrict__ B1,
    const _Float16* __restrict__ wp2, const float* __restrict__ B2,
    _Float16* __restrict__ hout, int n) {
    __shared__ __align__(16) _Float16 HA[2 * 64 * ST];
    int tid = threadIdx.x;
    int base = blockIdx.x * 64;
    int lane = tid & 63;
    int wv = tid >> 6;
    _Float16* s0 = HA + wv * 16 * ST;
    _Float16* s1 = HA + 64 * ST + wv * 16 * ST;

    gather_stage(hin4, rowptr, col, s0, s1, base, wv, lane, n);
    mfma_layer48(wp1, B1, s0, s1, lane);
    __builtin_amdgcn_wave_barrier();

    // layer 2 -> hout (f16), relu
    int am = lane & 15, q = lane >> 4;
    f16x8 a0 = *(const f16x8*)(s1 + am * ST + q * 8);
    f16x8 a1 = *(const f16x8*)(s1 + am * ST + 32 + q * 8);
    int g0 = base + wv * 16;
#pragma unroll
    for (int t = 0; t < 3; ++t) {
        f16x8 b0 = *(const f16x8*)(wp2 + ((q) * 48 + t * 16 + am) * 8);
        f16x8 b1 = *(const f16x8*)(wp2 + ((4 + q) * 48 + t * 16 + am) * 8);
        float bv = B2[t * 16 + am];
        f32x4 c = {bv, bv, bv, bv};
        c = __builtin_amdgcn_mfma_f32_16x16x32_f16(a0, b0, c, 0, 0, 0);
        c = __builtin_amdgcn_mfma_f32_16x16x32_f16(a1, b1, c, 0, 0, 0);
#pragma unroll
        for (int r = 0; r < 4; ++r) {
            int node = g0 + q * 4 + r;
            if (node < n) {
                float v = fmaxf(c[r], 0.f);
                hout[(size_t)node * D + t * 16 + am] = (_Float16)v;
            }
        }
    }
}

// tail: gather + conv3 MLP (48->48->48 relu) + head (48->48 relu -> 16), f32 out
__global__ __launch_bounds__(256) void tail_fused(
    const uint4* __restrict__ hin4, const int* __restrict__ rowptr,
    const int* __restrict__ col,
    const _Float16* __restrict__ wp1, const float* __restrict__ B1,
    const _Float16* __restrict__ wp2, const float* __restrict__ B2,
    const _Float16* __restrict__ wp3, const float* __restrict__ B3,
    const _Float16* __restrict__ wp4, const float* __restrict__ B4,
    float* __restrict__ out, int n) {
    __shared__ __align__(16) _Float16 HA[2 * 64 * ST];
    int tid = threadIdx.x;
    int base = blockIdx.x * 64;
    int lane = tid & 63;
    int wv = tid >> 6;
    _Float16* s0 = HA + wv * 16 * ST;
    _Float16* s1 = HA + 64 * ST + wv * 16 * ST;

    gather_stage(hin4, rowptr, col, s0, s1, base, wv, lane, n);
    mfma_layer48(wp1, B1, s0, s1, lane);
    __builtin_amdgcn_wave_barrier();
    mfma_layer48(wp2, B2, s1, s0, lane);
    __builtin_amdgcn_wave_barrier();
    mfma_layer48(wp3, B3, s0, s1, lane);
    __builtin_amdgcn_wave_barrier();

    // final 48 -> 16, no relu, f32 out
    int am = lane & 15, q = lane >> 4;
    f16x8 a0 = *(const f16x8*)(s1 + am * ST + q * 8);
    f16x8 a1 = *(const f16x8*)(s1 + am * ST + 32 + q * 8);
    f16x8 b0 = *(const f16x8*)(wp4 + ((q) * 16 + am) * 8);
    f16x8 b1 = *(const f16x8*)(wp4 + ((4 + q) * 16 + am) * 8);
    float bv = B4[am];
    f32x4 c = {bv, bv, bv, bv};
    c = __builtin_amdgcn_mfma_f32_16x16x32_f16(a0, b0, c, 0, 0, 0);
    c = __builtin_amdgcn_mfma_f32_16x16x32_f16(a1, b1, c, 0, 0, 0);
    int g0 = base + wv * 16;
#pragma unroll
    for (int r = 0; r < 4; ++r) {
        int node = g0 + q * 4 + r;
        if (node < n) out[(size_t)node * 16 + am] = c[r];
    }
}

// ---------------- launch ----------------

extern "C" void kernel_launch(void* const* d_in, const int* in_sizes, int n_in,
                              void* d_out, int out_size, void* d_ws, size_t ws_size,
                              hipStream_t stream) {
    const int n = NN, e = NE;
    const float* x = (const float*)d_in[0];
    const int* ei = (const int*)d_in[1];
    const int* src = ei;
    const int* dst = ei + e;
    const float* w11 = (const float*)d_in[2];
    const float* b11 = (const float*)d_in[3];
    const float* w12 = (const float*)d_in[4];
    const float* b12 = (const float*)d_in[5];
    const float* w21 = (const float*)d_in[6];
    const float* b21 = (const float*)d_in[7];
    const float* w22 = (const float*)d_in[8];
    const float* b22 = (const float*)d_in[9];
    const float* w31 = (const float*)d_in[10];
    const float* b31 = (const float*)d_in[11];
    const float* w32 = (const float*)d_in[12];
    const float* b32 = (const float*)d_in[13];
    const float* wf1 = (const float*)d_in[14];
    const float* bf1 = (const float*)d_in[15];
    const float* wf2 = (const float*)d_in[16];
    const float* bf2 = (const float*)d_in[17];
    float* out = (float*)d_out;

    // workspace: ping-pong f16 feature buffers (fusion makes in-place a
    // cross-block race: gather reads random rows while others write)
    uint4* HAa = (uint4*)d_ws;                        // N*6 uint4
    uint4* HAb = HAa + (size_t)n * 6;                 // N*6 uint4
    _Float16* WP = (_Float16*)(HAb + (size_t)n * 6);  // 8*3072 packed weights
    int* rowptr = (int*)(WP + 8 * 3072);              // N+1
    int* colidx = rowptr + (n + 1);                   // E
    int* arena = colidx + e;                          // NBK*CAP
    int* bucketLen = arena + (size_t)NBK * CAP;       // NBK
    int* bucketBase = bucketLen + NBK;                // NBK+1
    size_t needed = (size_t)((char*)(bucketBase + NBK + 1) - (char*)d_ws);
    if (needed > ws_size) return;

    const _Float16* wp11 = WP + 0 * 3072;
    const _Float16* wp12 = WP + 1 * 3072;
    const _Float16* wp21 = WP + 2 * 3072;
    const _Float16* wp22 = WP + 3 * 3072;
    const _Float16* wp31 = WP + 4 * 3072;
    const _Float16* wp32 = WP + 5 * 3072;
    const _Float16* wpf1 = WP + 6 * 3072;
    const _Float16* wpf2 = WP + 7 * 3072;

    // ---- prep + binned CSR build (4 dispatches) ----
    int gPrep = 9 + (n * 6 + 255) / 256;
    prep<<<gPrep, 256, 0, stream>>>(x, w11, w12, w21, w22, w31, w32, wf1, wf2,
                                    WP, HAa, bucketLen);
    bin_scatter<<<(e + EPB - 1) / EPB, 256, 0, stream>>>(src, dst, bucketLen, arena);
    scan_buckets_par<<<1, 512, 0, stream>>>(bucketLen, bucketBase, rowptr);
    csr_from_bins<<<NBK, 256, 0, stream>>>(arena, bucketLen, bucketBase, rowptr, colidx);

    int gConv = (n + 63) / 64;  // 64 nodes per block, 4 waves (16-node slabs)

    // ---- 3 fused convs (ping-pong HAa <-> HAb) ----
    conv_fused<<<gConv, 256, 0, stream>>>(HAa, rowptr, colidx,
                                          wp11, b11, wp12, b12, (_Float16*)HAb, n);
    conv_fused<<<gConv, 256, 0, stream>>>(HAb, rowptr, colidx,
                                          wp21, b21, wp22, b22, (_Float16*)HAa, n);
    tail_fused<<<gConv, 256, 0, stream>>>(HAa, rowptr, colidx,
                                          wp31, b31, wp32, b32,
                                          wpf1, bf1, wpf2, bf2, out, n);
}

// Round 5
// 273.531 us; speedup vs baseline: 5.4655x; 1.0274x over previous
//
#include <hip/hip_runtime.h>

#define NN 100000
#define NE 1600000
#define D 48
#define BK_SHIFT 8
#define BK_NODES 256
#define NBK 391       // ceil(NN / 256)
#define CAP 5120      // per-bucket arena capacity; expected 4096, sd ~64
#define EPB 4096      // edges per block in binning pass
#define NBINB 391     // ceil(NE / EPB)
#define ST 72         // LDS activation row stride in f16

typedef _Float16 f16x8 __attribute__((ext_vector_type(8)));
typedef float f32x4 __attribute__((ext_vector_type(4)));

// ---------------- fused prep + bin: blocks 0..NBINB-1 bin edges into per-bucket
// arenas; blocks NBINB..NBINB+7 pack weights; rest convert x -> f16.
// bucketLen is pre-zeroed by hipMemsetAsync. colidx is CAP-strided per bucket,
// so no global bucket prefix scan is needed (scan kernel deleted).

__global__ __launch_bounds__(256) void prepbin(
    const int* __restrict__ src, const int* __restrict__ dst,
    int* __restrict__ bucketLen, int* __restrict__ arena,
    const float* __restrict__ x,
    const float* __restrict__ w11, const float* __restrict__ w12,
    const float* __restrict__ w21, const float* __restrict__ w22,
    const float* __restrict__ w31, const float* __restrict__ w32,
    const float* __restrict__ wf1, const float* __restrict__ wf2,
    _Float16* __restrict__ wp, uint4* __restrict__ outh) {
    __shared__ int sCnt[NBK];
    __shared__ int sBase[NBK];
    int b = blockIdx.x;
    int tid = threadIdx.x;
    if (b < NBINB) {
        // ---- bin edges by dst>>8; packed word: (dstlocal 8b << 17) | src ----
        for (int i = tid; i < NBK; i += 256) sCnt[i] = 0;
        __syncthreads();
        int e0 = b * EPB;
        int eend = e0 + EPB;
        if (eend > NE) eend = NE;
        for (int i = e0 + tid; i < eend; i += 256) atomicAdd(&sCnt[dst[i] >> BK_SHIFT], 1);
        __syncthreads();
        for (int i = tid; i < NBK; i += 256) sBase[i] = atomicAdd(&bucketLen[i], sCnt[i]);
        __syncthreads();
        for (int i = tid; i < NBK; i += 256) sCnt[i] = 0;
        __syncthreads();
        for (int i = e0 + tid; i < eend; i += 256) {
            int d = dst[i];
            int bk = d >> BK_SHIFT;
            int off = atomicAdd(&sCnt[bk], 1) + sBase[bk];
            if (off < CAP) arena[bk * CAP + off] = ((d & (BK_NODES - 1)) << 17) | src[i];
        }
    } else if (b < NBINB + 8) {
        int l = b - NBINB;
        const float* W;
        int NL = 48;
        switch (l) {
            case 0: W = w11; break;
            case 1: W = w12; break;
            case 2: W = w21; break;
            case 3: W = w22; break;
            case 4: W = w31; break;
            case 5: W = w32; break;
            case 6: W = wf1; break;
            default: W = wf2; NL = 16; break;
        }
        _Float16* T = wp + l * 3072;
        int total = 64 * NL;  // (8 k-groups * 8 j) * NL
        for (int i = tid; i < total; i += 256) {
            int j = i & 7;
            int m = i >> 3;
            int g = m / NL;
            int nn = m - g * NL;
            int k = g * 8 + j;
            T[i] = (k < 48) ? (_Float16)W[k * NL + nn] : (_Float16)0.f;
        }
    } else {
        int i = (b - NBINB - 8) * 256 + tid;
        if (i < NN * 6) {
            const float4* p = (const float4*)(x + (size_t)i * 8);
            float4 a = p[0], bb = p[1];
            union { _Float16 h[8]; uint4 u; } pk;
            pk.h[0] = (_Float16)a.x; pk.h[1] = (_Float16)a.y;
            pk.h[2] = (_Float16)a.z; pk.h[3] = (_Float16)a.w;
            pk.h[4] = (_Float16)bb.x; pk.h[5] = (_Float16)bb.y;
            pk.h[6] = (_Float16)bb.z; pk.h[7] = (_Float16)bb.w;
            outh[i] = pk.u;
        }
    }
}

// ---------------- per-bucket CSR into CAP-strided colidx ----------------
// rowptr[node] = b*CAP + bucket-local exclusive prefix. End-of-list for the
// bucket-last node comes from bucketLen at gather time (no rowptr[NN] needed).

__global__ __launch_bounds__(256) void csr_from_bins(
    const int* __restrict__ arena, const int* __restrict__ bucketLen,
    int* __restrict__ rowptr, int* __restrict__ colidx) {
    __shared__ int sCnt[BK_NODES];
    __shared__ int sTot[256];
    int b = blockIdx.x;
    int tid = threadIdx.x;
    int len = bucketLen[b];
    if (len > CAP) len = CAP;
    const int* ar = arena + (size_t)b * CAP;
    int colBase = b * CAP;
    int nodeBase = b << BK_SHIFT;

    sCnt[tid] = 0;
    __syncthreads();
    for (int i = tid; i < len; i += 256) atomicAdd(&sCnt[ar[i] >> 17], 1);
    __syncthreads();

    int mine = sCnt[tid];
    sTot[tid] = mine;
    __syncthreads();
    for (int off = 1; off < 256; off <<= 1) {
        int add = 0;
        if (tid >= off) add = sTot[tid - off];
        __syncthreads();
        if (tid >= off) sTot[tid] += add;
        __syncthreads();
    }
    int excl = sTot[tid] - mine;
    int node = nodeBase + tid;
    if (node < NN) rowptr[node] = colBase + excl;
    __syncthreads();
    sCnt[tid] = colBase + excl;
    __syncthreads();
    for (int i = tid; i < len; i += 256) {
        int p = ar[i];
        int pos = atomicAdd(&sCnt[p >> 17], 1);
        colidx[pos] = p & 0x1FFFF;
    }
}

// ---------------- MFMA layer (unchanged, m89-verified mappings) ----------------
// A-frag: m = lane&15, k = (lane>>4)*8 + j; B-frag n = lane&15, same k;
// C/D: col n = lane&15, row m = (lane>>4)*4 + r.

__device__ __forceinline__ void mfma_layer48(
    const _Float16* __restrict__ wp, const float* __restrict__ bias,
    const _Float16* src, _Float16* dst, int lane) {
    int am = lane & 15, q = lane >> 4;
    f16x8 a0 = *(const f16x8*)(src + am * ST + q * 8);
    f16x8 a1 = *(const f16x8*)(src + am * ST + 32 + q * 8);
#pragma unroll
    for (int t = 0; t < 3; ++t) {
        f16x8 b0 = *(const f16x8*)(wp + ((q) * 48 + t * 16 + am) * 8);
        f16x8 b1 = *(const f16x8*)(wp + ((4 + q) * 48 + t * 16 + am) * 8);
        float bv = bias[t * 16 + am];
        f32x4 c = {bv, bv, bv, bv};
        c = __builtin_amdgcn_mfma_f32_16x16x32_f16(a0, b0, c, 0, 0, 0);
        c = __builtin_amdgcn_mfma_f32_16x16x32_f16(a1, b1, c, 0, 0, 0);
#pragma unroll
        for (int r = 0; r < 4; ++r) {
            float v = fmaxf(c[r], 0.f);
            dst[(q * 4 + r) * ST + t * 16 + am] = (_Float16)v;
        }
    }
}

// ---------------- fused gather + stage v3: paired node chains ----------------
// lane = c*8+s; s = edge slot (8 edges/batch), c = 16B chunk of the 96B row.
// Two NODES (nl, nl+1) processed concurrently: 4 independent feature loads +
// 4 col loads in flight per lane (MLP probe vs the saturated miss path).
// node0 is always even (base, wv*16, nl even) -> never bucket-last; only node1
// needs the bucket-end (bend) boundary from bucketLen (CAP-strided colidx).

__device__ __forceinline__ void gather_stage(const uint4* __restrict__ hin4,
                                             const int* __restrict__ rowptr,
                                             const int* __restrict__ col,
                                             int bend,
                                             _Float16* s0, _Float16* s1,
                                             int base, int wv, int lane, int n) {
    // zero K-pad halves (cols 48..71) of both slabs, 16B stores
    for (int i = lane; i < 16 * 3; i += 64) {
        int r = i / 3, cq = i % 3;
        *(uint4*)(s0 + r * ST + 48 + cq * 8) = make_uint4(0u, 0u, 0u, 0u);
        *(uint4*)(s1 + r * ST + 48 + cq * 8) = make_uint4(0u, 0u, 0u, 0u);
    }
    int s = lane & 7;   // edge slot
    int c = lane >> 3;  // row chunk (0..5 active, 6..7 idle)
    bool act = (c < 6);
    int cc = act ? c : 0;
    int nb = base + wv * 16;
    for (int nl = 0; nl < 16; nl += 2) {
        int node0 = nb + nl;
        int node1 = node0 + 1;
        f16x8 acc0 = {0, 0, 0, 0, 0, 0, 0, 0};
        f16x8 acc1 = {0, 0, 0, 0, 0, 0, 0, 0};
        int e00 = 0, e01 = 0, e10 = 0, e11 = 0;
        if (node0 < n) {
            e00 = rowptr[node0];
            e01 = rowptr[node0 + 1];  // node0 even -> never bucket-last
        }
        if (node1 < n) {
            e10 = e01;
            e11 = ((node1 & (BK_NODES - 1)) == BK_NODES - 1 || node1 == n - 1)
                      ? bend : rowptr[node1 + 1];
        }
        if (act) {
            int ebA = e00, ebB = e10;
            while (ebA < e01 || ebB < e11) {
                int eA0 = ebA + s, eA1 = ebA + 8 + s;
                int eB0 = ebB + s, eB1 = ebB + 8 + s;
                bool okA0 = eA0 < e01, okA1 = eA1 < e01;
                bool okB0 = eB0 < e11, okB1 = eB1 < e11;
                // mask keeps index in-workspace even on uninitialized slack reads
                int iA0 = col[okA0 ? eA0 : e00] & 0x1FFFF;
                int iA1 = col[okA1 ? eA1 : e00] & 0x1FFFF;
                int iB0 = col[okB0 ? eB0 : e10] & 0x1FFFF;
                int iB1 = col[okB1 ? eB1 : e10] & 0x1FFFF;
                uint4 vA0 = hin4[(size_t)iA0 * 6 + cc];
                uint4 vA1 = hin4[(size_t)iA1 * 6 + cc];
                uint4 vB0 = hin4[(size_t)iB0 * 6 + cc];
                uint4 vB1 = hin4[(size_t)iB1 * 6 + cc];
                if (!okA0) vA0 = make_uint4(0u, 0u, 0u, 0u);
                if (!okA1) vA1 = make_uint4(0u, 0u, 0u, 0u);
                if (!okB0) vB0 = make_uint4(0u, 0u, 0u, 0u);
                if (!okB1) vB1 = make_uint4(0u, 0u, 0u, 0u);
                acc0 += *(const f16x8*)&vA0;
                acc0 += *(const f16x8*)&vA1;
                acc1 += *(const f16x8*)&vB0;
                acc1 += *(const f16x8*)&vB1;
                ebA += 16;
                ebB += 16;
            }
        }
        // reduce over the 8 edge slots (xor tree on s; c preserved since m<8)
        union { f16x8 f; int i[4]; } a0, a1, bx;
        a0.f = acc0;
        a1.f = acc1;
#pragma unroll
        for (int m = 1; m <= 4; m <<= 1) {
            bx.i[0] = __shfl_xor(a0.i[0], m);
            bx.i[1] = __shfl_xor(a0.i[1], m);
            bx.i[2] = __shfl_xor(a0.i[2], m);
            bx.i[3] = __shfl_xor(a0.i[3], m);
            a0.f += bx.f;
            bx.i[0] = __shfl_xor(a1.i[0], m);
            bx.i[1] = __shfl_xor(a1.i[1], m);
            bx.i[2] = __shfl_xor(a1.i[2], m);
            bx.i[3] = __shfl_xor(a1.i[3], m);
            a1.f += bx.f;
        }
        if (s == 0 && act) {
            union { f16x8 f; uint4 u; } r0, r1;
            r0.f = (f16x8){0, 0, 0, 0, 0, 0, 0, 0};
            r1.f = (f16x8){0, 0, 0, 0, 0, 0, 0, 0};
            if (node0 < n) {
                uint4 self = hin4[(size_t)node0 * 6 + c];
                r0.f = a0.f + *(const f16x8*)&self;
            }
            if (node1 < n) {
                uint4 self = hin4[(size_t)node1 * 6 + c];
                r1.f = a1.f + *(const f16x8*)&self;
            }
            *(uint4*)(s0 + nl * ST + c * 8) = r0.u;
            *(uint4*)(s0 + (nl + 1) * ST + c * 8) = r1.u;
        }
    }
    __builtin_amdgcn_wave_barrier();  // scheduling fence (wave-lockstep LDS idiom)
}

// conv: gather+self -> relu(@W1+b1) -> relu(@W2+b2) -> f16 features (ping-pong)
__global__ __launch_bounds__(256) void conv_fused(
    const uint4* __restrict__ hin4, const int* __restrict__ rowptr,
    const int* __restrict__ col, const int* __restrict__ bucketLen,
    const _Float16* __restrict__ wp1, const float* __restrict__ B1,
    const _Float16* __restrict__ wp2, const float* __restrict__ B2,
    _Float16* __restrict__ hout, int n) {
    __shared__ __align__(16) _Float16 HA[2 * 64 * ST];
    int tid = threadIdx.x;
    int base = blockIdx.x * 64;
    int lane = tid & 63;
    int wv = tid >> 6;
    _Float16* s0 = HA + wv * 16 * ST;
    _Float16* s1 = HA + 64 * ST + wv * 16 * ST;

    int bucket = base >> BK_SHIFT;
    int blen = bucketLen[bucket];
    if (blen > CAP) blen = CAP;
    int bend = bucket * CAP + blen;

    gather_stage(hin4, rowptr, col, bend, s0, s1, base, wv, lane, n);
    mfma_layer48(wp1, B1, s0, s1, lane);
    __builtin_amdgcn_wave_barrier();

    // layer 2 -> hout (f16), relu
    int am = lane & 15, q = lane >> 4;
    f16x8 a0 = *(const f16x8*)(s1 + am * ST + q * 8);
    f16x8 a1 = *(const f16x8*)(s1 + am * ST + 32 + q * 8);
    int g0 = base + wv * 16;
#pragma unroll
    for (int t = 0; t < 3; ++t) {
        f16x8 b0 = *(const f16x8*)(wp2 + ((q) * 48 + t * 16 + am) * 8);
        f16x8 b1 = *(const f16x8*)(wp2 + ((4 + q) * 48 + t * 16 + am) * 8);
        float bv = B2[t * 16 + am];
        f32x4 c = {bv, bv, bv, bv};
        c = __builtin_amdgcn_mfma_f32_16x16x32_f16(a0, b0, c, 0, 0, 0);
        c = __builtin_amdgcn_mfma_f32_16x16x32_f16(a1, b1, c, 0, 0, 0);
#pragma unroll
        for (int r = 0; r < 4; ++r) {
            int node = g0 + q * 4 + r;
            if (node < n) {
                float v = fmaxf(c[r], 0.f);
                hout[(size_t)node * D + t * 16 + am] = (_Float16)v;
            }
        }
    }
}

// tail: gather + conv3 MLP (48->48->48 relu) + head (48->48 relu -> 16), f32 out
__global__ __launch_bounds__(256) void tail_fused(
    const uint4* __restrict__ hin4, const int* __restrict__ rowptr,
    const int* __restrict__ col, const int* __restrict__ bucketLen,
    const _Float16* __restrict__ wp1, const float* __restrict__ B1,
    const _Float16* __restrict__ wp2, const float* __restrict__ B2,
    const _Float16* __restrict__ wp3, const float* __restrict__ B3,
    const _Float16* __restrict__ wp4, const float* __restrict__ B4,
    float* __restrict__ out, int n) {
    __shared__ __align__(16) _Float16 HA[2 * 64 * ST];
    int tid = threadIdx.x;
    int base = blockIdx.x * 64;
    int lane = tid & 63;
    int wv = tid >> 6;
    _Float16* s0 = HA + wv * 16 * ST;
    _Float16* s1 = HA + 64 * ST + wv * 16 * ST;

    int bucket = base >> BK_SHIFT;
    int blen = bucketLen[bucket];
    if (blen > CAP) blen = CAP;
    int bend = bucket * CAP + blen;

    gather_stage(hin4, rowptr, col, bend, s0, s1, base, wv, lane, n);
    mfma_layer48(wp1, B1, s0, s1, lane);
    __builtin_amdgcn_wave_barrier();
    mfma_layer48(wp2, B2, s1, s0, lane);
    __builtin_amdgcn_wave_barrier();
    mfma_layer48(wp3, B3, s0, s1, lane);
    __builtin_amdgcn_wave_barrier();

    // final 48 -> 16, no relu, f32 out
    int am = lane & 15, q = lane >> 4;
    f16x8 a0 = *(const f16x8*)(s1 + am * ST + q * 8);
    f16x8 a1 = *(const f16x8*)(s1 + am * ST + 32 + q * 8);
    f16x8 b0 = *(const f16x8*)(wp4 + ((q) * 16 + am) * 8);
    f16x8 b1 = *(const f16x8*)(wp4 + ((4 + q) * 16 + am) * 8);
    float bv = B4[am];
    f32x4 c = {bv, bv, bv, bv};
    c = __builtin_amdgcn_mfma_f32_16x16x32_f16(a0, b0, c, 0, 0, 0);
    c = __builtin_amdgcn_mfma_f32_16x16x32_f16(a1, b1, c, 0, 0, 0);
    int g0 = base + wv * 16;
#pragma unroll
    for (int r = 0; r < 4; ++r) {
        int node = g0 + q * 4 + r;
        if (node < n) out[(size_t)node * 16 + am] = c[r];
    }
}

// ---------------- launch ----------------

extern "C" void kernel_launch(void* const* d_in, const int* in_sizes, int n_in,
                              void* d_out, int out_size, void* d_ws, size_t ws_size,
                              hipStream_t stream) {
    const int n = NN, e = NE;
    const float* x = (const float*)d_in[0];
    const int* ei = (const int*)d_in[1];
    const int* src = ei;
    const int* dst = ei + e;
    const float* w11 = (const float*)d_in[2];
    const float* b11 = (const float*)d_in[3];
    const float* w12 = (const float*)d_in[4];
    const float* b12 = (const float*)d_in[5];
    const float* w21 = (const float*)d_in[6];
    const float* b21 = (const float*)d_in[7];
    const float* w22 = (const float*)d_in[8];
    const float* b22 = (const float*)d_in[9];
    const float* w31 = (const float*)d_in[10];
    const float* b31 = (const float*)d_in[11];
    const float* w32 = (const float*)d_in[12];
    const float* b32 = (const float*)d_in[13];
    const float* wf1 = (const float*)d_in[14];
    const float* bf1 = (const float*)d_in[15];
    const float* wf2 = (const float*)d_in[16];
    const float* bf2 = (const float*)d_in[17];
    float* out = (float*)d_out;

    // workspace: ping-pong f16 feature buffers + packed weights + CSR
    // (colidx CAP-strided per bucket: no bucket prefix scan needed)
    uint4* HAa = (uint4*)d_ws;                        // N*6 uint4
    uint4* HAb = HAa + (size_t)n * 6;                 // N*6 uint4
    _Float16* WP = (_Float16*)(HAb + (size_t)n * 6);  // 8*3072 packed weights
    int* rowptr = (int*)(WP + 8 * 3072);              // N+1
    int* colidx = rowptr + (n + 1);                   // NBK*CAP (strided)
    int* arena = colidx + (size_t)NBK * CAP;          // NBK*CAP
    int* bucketLen = arena + (size_t)NBK * CAP;       // NBK
    size_t needed = (size_t)((char*)(bucketLen + NBK) - (char*)d_ws);
    if (needed > ws_size) return;

    const _Float16* wp11 = WP + 0 * 3072;
    const _Float16* wp12 = WP + 1 * 3072;
    const _Float16* wp21 = WP + 2 * 3072;
    const _Float16* wp22 = WP + 3 * 3072;
    const _Float16* wp31 = WP + 4 * 3072;
    const _Float16* wp32 = WP + 5 * 3072;
    const _Float16* wpf1 = WP + 6 * 3072;
    const _Float16* wpf2 = WP + 7 * 3072;

    // ---- fused prep+bin, then per-bucket CSR (2 dispatches + 1 memset) ----
    hipMemsetAsync(bucketLen, 0, NBK * sizeof(int), stream);
    int gPB = NBINB + 8 + (n * 6 + 255) / 256;
    prepbin<<<gPB, 256, 0, stream>>>(src, dst, bucketLen, arena, x,
                                     w11, w12, w21, w22, w31, w32, wf1, wf2,
                                     WP, HAa);
    csr_from_bins<<<NBK, 256, 0, stream>>>(arena, bucketLen, rowptr, colidx);

    int gConv = (n + 63) / 64;  // 64 nodes per block, 4 waves (16-node slabs)

    // ---- 3 fused convs (ping-pong HAa <-> HAb) ----
    conv_fused<<<gConv, 256, 0, stream>>>(HAa, rowptr, colidx, bucketLen,
                                          wp11, b11, wp12, b12, (_Float16*)HAb, n);
    conv_fused<<<gConv, 256, 0, stream>>>(HAb, rowptr, colidx, bucketLen,
                                          wp21, b21, wp22, b22, (_Float16*)HAa, n);
    tail_fused<<<gConv, 256, 0, stream>>>(HAa, rowptr, colidx, bucketLen,
                                          wp31, b31, wp32, b32,
                                          wpf1, bf1, wpf2, bf2, out, n);
}